// Round 10
// baseline (239.186 us; speedup 1.0000x reference)
//
#include <hip/hip_runtime.h>
#include <math.h>

#define N_     325
#define BN_    10400
#define OUTSZ_ (BN_*12)   // 124800
#define RB_    208        // rows per block (13 waves x 16)
#define WV_    13
#define THR_   832

// R22 structure: R19/R21 GRU with (a) fused output (atomicAdd into out, ws+mix
// kernel deleted; out zeroed via hipMemsetAsync on the stream) and (b) the
// h-plane reverted to padded-144B stride (R21's col-swizzle RAISED conflicts
// 1.47M->6.46M).
// WHY NOTHING ELSE: R13(16w/CU,DS-light), R17(24w), R18-21(13w,DS-heavy) all
// hit 173+-1us -> the invariant is the TRANS pipe: 159.7M elements x 5 trans
// (3 exp2 + 2 rcp, minimal for exact GRU) x 8cyc(1/4-rate wave64) / 256 CU
// = 162 us/CU floor. Kernel is ~7% above it; occupancy/DS/grid shaping are
// dead levers. This round harvests the 55us bench-vs-kernel gap (mix kernel
// + launch + ws round-trip).

typedef _Float16 h8v  __attribute__((ext_vector_type(8)));  // 8 f16 (4 VGPRs)
typedef float    f4v  __attribute__((ext_vector_type(4)));  // 4 fp32 acc
typedef unsigned int u32x4 __attribute__((ext_vector_type(4)));

#define L1C 1.4426950408889634f    // log2(e)
#define L2C 2.8853900817779268f    // 2*log2(e)

__device__ __forceinline__ float rcp_f(float x){ return __builtin_amdgcn_rcpf(x); }
#if __has_builtin(__builtin_amdgcn_exp2f)
__device__ __forceinline__ float exp2_f(float x){ return __builtin_amdgcn_exp2f(x); }
#else
__device__ __forceinline__ float exp2_f(float x){ return __expf(x * 0.6931471805599453f); }
#endif

__device__ __forceinline__ unsigned short f16u(float x){
    union { _Float16 h; unsigned short u; } cv; cv.h = (_Float16)x; return cv.u;
}

// ---------------- LDS layout (bytes) ----------------
// [BOFF,  +24576) 24 main B frags: f*1024 + lane*16 (shared by 13 waves)
// [EOFF,  +3072 ) 12 ext  B frags: e*256 + (lane&15)*16
// [HOFF,  +29952) per-wave h plane: w*2304; byte = row*144 + col*2 (16r x 64c, pad 8)
// [XOFF,  +9984 ) x packed f16 pair: row*48 + t*4
// [WOFF,  +832  ) softmax weight per row
// [LOFF,  +832  ) lv broadcast: w*64 + idx*4 (intra-wave only)
// [LWOFF, +128  ) dec linW frags, compressed: ch*64 + kg*16
#define BOFF   0
#define EOFF   24576
#define HOFF   27648
#define XOFF   57600
#define WOFF   67584
#define LOFF   68416
#define LWOFF  69248
#define SMEMSZ 69376

#define MFMA(A,B,C) __builtin_amdgcn_mfma_f32_16x16x32_f16((A),(B),(C),0,0,0)

// Stage 192x64 f32 Whh (one cluster) into 24 pre-swizzled f16 B-frags, scaled:
// r,z rows by -log2e; n rows by -2log2e. CONFLICT-FREE: thread writes one full
// 16-B block at linearly increasing LDS address. Frag mapping preserved:
// frag f = g*8+ct*2+ch; lane (kg*16+l15) holds col=ct*16+l15, k=ch*32+kg*8+j.
__device__ __forceinline__ void stage_main(const float* __restrict__ W, char* smem, int tid)
{
#pragma unroll
    for (int it = 0; it < 2; ++it) {
        int a16 = it*THR_ + tid;           // 16-B block index in [0,1536)
        if (a16 < 1536) {
            int f     = a16 >> 6;          // frag 0..23
            int lanew = a16 & 63;          // dest lane slot
            int colf  = lanew & 15;
            int kb4   = lanew >> 4;
            int ch    = f & 1;
            int ct    = (f >> 1) & 3;
            int g     = f >> 3;
            int gc    = g*64 + ct*16 + colf;   // weight row 0..191
            int k0    = ch*32 + kb4*8;
            float sc  = (g < 2) ? -L1C : -L2C;
            const float* p = W + gc*64 + k0;
            float4 a = *(const float4*)p;
            float4 b = *(const float4*)(p+4);
            h8v v;
            v[0]=(_Float16)(sc*a.x); v[1]=(_Float16)(sc*a.y);
            v[2]=(_Float16)(sc*a.z); v[3]=(_Float16)(sc*a.w);
            v[4]=(_Float16)(sc*b.x); v[5]=(_Float16)(sc*b.y);
            v[6]=(_Float16)(sc*b.z); v[7]=(_Float16)(sc*b.w);
            *(h8v*)(smem + BOFF + a16*16) = v;
        }
    }
}

// One recurrence step for one wave: 36 MFMA + gate algebra, 16 rows x 64 cols.
// wp = h-plane write base (hp + kg*576 + l15*2), hreg = fp32 carry [ct][i].
__device__ __forceinline__ void rnn_step(h8v Aeh, h8v Ah0, h8v Ah1,
                                         const char* bb, const char* eb,
                                         const float cbh[4], float (&hreg)[4][4],
                                         char* wp)
{
    const f4v Z0 = {0.f,0.f,0.f,0.f};
#pragma unroll
    for (int ct = 0; ct < 4; ++ct) {
        f4v a0 = MFMA(Aeh, *(const h8v*)(eb + ct*256),       Z0);   // r: ext (Wih,b)
        a0 = MFMA(Ah0, *(const h8v*)(bb + (ct*2   )*1024), a0);     // r: Whh ch0
        a0 = MFMA(Ah1, *(const h8v*)(bb + (ct*2+1 )*1024), a0);     // r: Whh ch1
        f4v a1 = MFMA(Aeh, *(const h8v*)(eb + (4+ct)*256),   Z0);   // z
        a1 = MFMA(Ah0, *(const h8v*)(bb + (8+ct*2 )*1024), a1);
        a1 = MFMA(Ah1, *(const h8v*)(bb + (9+ct*2 )*1024), a1);
        f4v a3 = MFMA(Aeh, *(const h8v*)(eb + (8+ct)*256),   Z0);   // n: gi part
        f4v a2 = MFMA(Ah0, *(const h8v*)(bb + (16+ct*2)*1024), Z0); // n: Whh.h
        a2 = MFMA(Ah1, *(const h8v*)(bb + (17+ct*2)*1024), a2);
#pragma unroll
        for (int i = 0; i < 4; ++i) {
            float er = exp2_f(a0[i]);
            float rr = rcp_f(1.0f + er);
            float ez = exp2_f(a1[i]);
            float en = exp2_f(fmaf(rr, a2[i] + cbh[ct], a3[i]));
            float h  = hreg[ct][i];
            float aa = 1.0f + ez;
            float den = fmaf(en, aa, aa);        // (1+en)(1+ez)
            float t1  = fmaf(-en, ez, ez);       // ez(1-en)
            float t2  = fmaf(en, h, h);          // h(1+en)
            float hnew = (t1 + t2) * rcp_f(den);
            hreg[ct][i] = hnew;
            *(_Float16*)(wp + i*144 + 32*ct) = (_Float16)hnew;
        }
        __builtin_amdgcn_sched_barrier(0);       // no cross-ct acc overlap
    }
}

__global__ void __launch_bounds__(THR_, 8) krnn_kernel(
    const float* __restrict__ X,
    const float* __restrict__ eWih, const float* __restrict__ eWhh,
    const float* __restrict__ ebih, const float* __restrict__ ebhh,
    const float* __restrict__ dWih, const float* __restrict__ dWhh,
    const float* __restrict__ dbih, const float* __restrict__ dbhh,
    const float* __restrict__ linW, const float* __restrict__ linb,
    const float* __restrict__ embed, float* __restrict__ out)
{
    __shared__ __align__(16) char smem[SMEMSZ];

    const int c    = blockIdx.y;
    const int row0 = blockIdx.x * RB_;          // 208 rows per block
    const int tid  = threadIdx.x;
    const int lane = tid & 63;
    const int w    = tid >> 6;                  // wave 0..12
    const int l15  = lane & 15;
    const int kg   = lane >> 4;

    // ---------------- stage encoder weights / x / softmax / h=0 ----------------
    stage_main(eWhh + c*12288, smem, tid);

    if (tid < 192) {                            // enc ext: k0=Wih0,k1=Wih1,k2=bias
        int e = tid >> 4, ln = tid & 15;
        int g = e >> 2, ct = e & 3;
        int gc = g*64 + ct*16 + ln;
        float sc = (g < 2) ? -L1C : -L2C;
        float w0 = eWih[c*384 + gc*2], w1 = eWih[c*384 + gc*2 + 1];
        float bb_ = (g < 2) ? (ebih[c*192+gc] + ebhh[c*192+gc]) : ebih[c*192+gc];
        unsigned short* d = (unsigned short*)(smem + EOFF + e*256 + ln*16);
        d[0] = f16u(sc*w0); d[1] = f16u(sc*w1); d[2] = f16u(sc*bb_);
        d[3]=0; d[4]=0; d[5]=0; d[6]=0; d[7]=0;
    }
    for (int i = tid; i < RB_*12; i += THR_) {  // x: packed f16 (x0,x1) per (row,t)
        int r = i / 12, t = i - r*12;
        int rg = row0 + r;
        const float* p = X + (size_t)rg*24 + t*2;
        unsigned v = (unsigned)f16u(p[0]) | ((unsigned)f16u(p[1]) << 16);
        *(unsigned*)(smem + XOFF + r*48 + t*4) = v;
    }
    if (tid < RB_) {                            // softmax weight per row
        int r = row0 + tid;
        int n = r % N_;
        float e[10], mx = -1e30f;
#pragma unroll
        for (int cc=0; cc<10; ++cc){ e[cc]=embed[n*10+cc]; mx=fmaxf(mx,e[cc]); }
        float den = 0.0f;
#pragma unroll
        for (int cc=0; cc<10; ++cc) den += exp2_f((e[cc]-mx)*L1C);
        *(float*)(smem + WOFF + tid*4) = exp2_f((e[c]-mx)*L1C) * rcp_f(den);
    }
    for (int i = tid; i < WV_*576; i += THR_)   // zero all 13 h planes (incl. pad)
        *(unsigned*)(smem + HOFF + i*4) = 0u;

    float cbh[4];                               // n-gate bhh per owned col (fp32)
#pragma unroll
    for (int ct=0; ct<4; ++ct) cbh[ct] = -L2C * ebhh[c*192 + 128 + l15 + 16*ct];

    __syncthreads();                            // barrier 1/3

    char* hp = smem + HOFF + w*2304;            // private h plane
    const int rdo = l15*144 + kg*16;            // A-frag read offset (+64 for ch1)
    char* wp = hp + kg*576 + l15*2;             // gate write base
    const char* bb = smem + lane*16;            // main frag base
    const char* eb = smem + EOFF + l15*16;      // ext frag base (broadcast reads)

    float hreg[4][4];
#pragma unroll
    for (int ct=0; ct<4; ++ct)
#pragma unroll
        for (int i=0;i<4;++i) hreg[ct][i] = 0.0f;

    // ---------------- encoder: 12 barrier-free steps ----------------
    for (int t = 0; t < 12; ++t) {
        unsigned xd = *(const unsigned*)(smem + XOFF + (w*16 + l15)*48 + t*4);
        union { u32x4 u; h8v h; } ae;
        ae.u.x = (lane < 16) ? xd : 0u;         // k0=x0, k1=x1
        ae.u.y = (lane < 16) ? 0x00003C00u : 0u;// k2=1.0
        ae.u.z = 0u; ae.u.w = 0u;
        h8v Ah0 = *(const h8v*)(hp + rdo);
        h8v Ah1 = *(const h8v*)(hp + rdo + 64);
        rnn_step(ae.h, Ah0, Ah1, bb, eb, cbh, hreg, wp);
    }

    // lv0 = f16(x[t=11].x) packed with 1.0 for the dec A-ext
    unsigned aew = (*(const unsigned*)(smem + XOFF + (w*16 + l15)*48 + 44) & 0xFFFFu)
                   | 0x3C000000u;

    __syncthreads();                            // barrier 2/3 (all enc reads done)

    // ---------------- stage decoder weights ----------------
    stage_main(dWhh + c*12288, smem, tid);
    if (tid < 192) {                            // dec ext: k0=Wih, k1=bias
        int e = tid >> 4, ln = tid & 15;
        int g = e >> 2, ct = e & 3;
        int gc = g*64 + ct*16 + ln;
        float k0, k1;
        if (g < 2) { k0 = -L1C*dWih[c*192+gc]; k1 = -L1C*(dbih[c*192+gc]+dbhh[c*192+gc]); }
        else       { k0 = -L2C*dWih[c*192+gc]; k1 = -L2C*dbih[c*192+gc]; }
        unsigned short* d = (unsigned short*)(smem + EOFF + e*256 + ln*16);
        d[0] = f16u(k0); d[1] = f16u(k1);
        d[2]=0; d[3]=0; d[4]=0; d[5]=0; d[6]=0; d[7]=0;
    }
    if (tid < 8) {                              // linW frags, compressed [ch][kg]
        int ch = tid >> 2, k4 = tid & 3;
        unsigned short* d = (unsigned short*)(smem + LWOFF + ch*64 + k4*16);
#pragma unroll
        for (int j=0;j<8;++j) d[j] = f16u(linW[c*64 + ch*32 + k4*8 + j]);
    }
#pragma unroll
    for (int ct=0; ct<4; ++ct) cbh[ct] = -L2C * dbhh[c*192 + 128 + l15 + 16*ct];
    const float lb = linb[c];

    __syncthreads();                            // barrier 3/3

    // ---------------- decoder: 12 barrier-free steps ----------------
    for (int s = 0; s < 12; ++s) {
        h8v Ah0 = *(const h8v*)(hp + rdo);
        h8v Ah1 = *(const h8v*)(hp + rdo + 64);
        if (s > 0) {
            const f4v Zv = {0.f,0.f,0.f,0.f};
            f4v av = MFMA(Ah0, *(const h8v*)(smem + LWOFF + kg*16), Zv);
            av = MFMA(Ah1, *(const h8v*)(smem + LWOFF + 64 + kg*16), av);
            if (l15 == 0) {                     // lanes l15==0 own rows kg*4+i
#pragma unroll
                for (int i=0;i<4;++i) {
                    float lv = av[i] + lb;      // v_{s-1}
                    *(float*)(smem + LOFF + w*64 + (kg*4+i)*4) = lv;
                    int r = row0 + w*16 + kg*4 + i;
                    float wg = *(const float*)(smem + WOFF + (w*16 + kg*4 + i)*4);
                    atomicAdd(&out[(size_t)r*12 + (s-1)], wg*lv);
                }
            }
            float lvme = *(const float*)(smem + LOFF + w*64 + l15*4); // intra-wave
            aew = (unsigned)f16u(lvme) | 0x3C000000u;   // k0=lv, k1=1.0
        }
        union { u32x4 u; h8v h; } ae;
        ae.u.x = (lane < 16) ? aew : 0u;
        ae.u.y = 0u; ae.u.z = 0u; ae.u.w = 0u;
        rnn_step(ae.h, Ah0, Ah1, bb, eb, cbh, hreg, wp);
    }

    // ---------------- epilogue: v_11 from h_11 ----------------
    {
        h8v Ah0 = *(const h8v*)(hp + rdo);
        h8v Ah1 = *(const h8v*)(hp + rdo + 64);
        const f4v Zv = {0.f,0.f,0.f,0.f};
        f4v av = MFMA(Ah0, *(const h8v*)(smem + LWOFF + kg*16), Zv);
        av = MFMA(Ah1, *(const h8v*)(smem + LWOFF + 64 + kg*16), av);
        if (l15 == 0) {
#pragma unroll
            for (int i=0;i<4;++i) {
                float lv = av[i] + lb;
                int r = row0 + w*16 + kg*4 + i;
                float wg = *(const float*)(smem + WOFF + (w*16 + kg*4 + i)*4);
                atomicAdd(&out[(size_t)r*12 + 11], wg*lv);
            }
        }
    }
}

extern "C" void kernel_launch(void* const* d_in, const int* in_sizes, int n_in,
                              void* d_out, int out_size, void* d_ws, size_t ws_size,
                              hipStream_t stream) {
    // 0:A 1:X 2:enc_Wih 3:enc_Whh 4:enc_bih 5:enc_bhh
    // 6:dec_Wih 7:dec_Whh 8:dec_bih 9:dec_bhh 10:lin_W 11:lin_b 12:embed
    const float* X    = (const float*)d_in[1];
    const float* eWih = (const float*)d_in[2];
    const float* eWhh = (const float*)d_in[3];
    const float* ebih = (const float*)d_in[4];
    const float* ebhh = (const float*)d_in[5];
    const float* dWih = (const float*)d_in[6];
    const float* dWhh = (const float*)d_in[7];
    const float* dbih = (const float*)d_in[8];
    const float* dbhh = (const float*)d_in[9];
    const float* linW = (const float*)d_in[10];
    const float* linb = (const float*)d_in[11];
    const float* emb  = (const float*)d_in[12];
    float* out = (float*)d_out;

    hipMemsetAsync(d_out, 0, out_size, stream);   // atomics accumulate into out

    dim3 grid(BN_ / RB_, 10);   // 50 x 10 = 500 blocks
    krnn_kernel<<<grid, dim3(THR_), 0, stream>>>(
        X, eWih, eWhh, ebih, ebhh, dWih, dWhh, dbih, dbhh, linW, linb, emb, out);
}

// Round 11
// 220.566 us; speedup vs baseline: 1.0844x; 1.0844x over previous
//
#include <hip/hip_runtime.h>
#include <math.h>

#define N_     325
#define BN_    10400
#define OUTSZ_ (BN_*12)   // 124800

// R23 = Round-2's best-measured kernel (bench 224.5us, krnn 166us) with ONE
// change: conflict-free stage_main (R17's 16B-block linear-write version,
// adapted to 256 thr) to remove the 5.85M LDS bank-conflict cycles of the
// original word-wise staging. krnn at 166us sits ~2.5% above the trans-pipe
// floor (159.7M elem x 5 trans x 8cyc / 256 CU = 162us) -- confirmed invariant
// across R13/R17/R18/R19/R21 geometries (166-175us at 13-24 waves/CU). All
// structural levers (occupancy, rounds, LDS size, regs, output fusion) are
// measured-dead; R22's atomicAdd fusion cost +5us kernel / +39MB writes.
// Structure: wave-independent GRU, 4 waves x 16 rows x 64 cols per 256-thr
// block, private LDS h-plane (stride 144B), 3 barriers total, barrier-free
// 12+12 step loops, 5-trans gate algebra, fp32 h carry, ws + tiny mix kernel.

typedef _Float16 h8v  __attribute__((ext_vector_type(8)));  // 8 f16 (4 VGPRs)
typedef float    f4v  __attribute__((ext_vector_type(4)));  // 4 fp32 acc
typedef unsigned int u32x4 __attribute__((ext_vector_type(4)));

#define L1C 1.4426950408889634f    // log2(e)
#define L2C 2.8853900817779268f    // 2*log2(e)

__device__ __forceinline__ float rcp_f(float x){ return __builtin_amdgcn_rcpf(x); }
#if __has_builtin(__builtin_amdgcn_exp2f)
__device__ __forceinline__ float exp2_f(float x){ return __builtin_amdgcn_exp2f(x); }
#else
__device__ __forceinline__ float exp2_f(float x){ return __expf(x * 0.6931471805599453f); }
#endif

__device__ __forceinline__ unsigned short f16u(float x){
    union { _Float16 h; unsigned short u; } cv; cv.h = (_Float16)x; return cv.u;
}

// ---------------- LDS layout (bytes) ----------------
// [BOFF,  +24576) 24 main B frags: f*1024 + lane*16 (shared by 4 waves)
// [EOFF,  +3072 ) 12 ext  B frags: e*256 + (lane&15)*16
// [HOFF,  +9216 ) per-wave h plane: w*2304; byte = row*144 + col*2 (16r x 64c, pad 8)
// [XOFF,  +3072 ) x packed f16 pair: row*48 + t*4
// [LWOFF, +2048 ) dec linW frags (overlay on X): ch*1024 + lane*16
// [WOFF,  +256  ) softmax weight per row
// [LOFF,  +256  ) lv broadcast: w*64 + idx*4
#define BOFF   0
#define EOFF   24576
#define HOFF   27648
#define XOFF   36864
#define LWOFF  36864
#define WOFF   39936
#define LOFF   40192
#define SMEMSZ 40448

#define MFMA(A,B,C) __builtin_amdgcn_mfma_f32_16x16x32_f16((A),(B),(C),0,0,0)

// Stage 192x64 f32 Whh (one cluster) into 24 pre-swizzled f16 B-frags, scaled:
// r,z rows by -log2e; n rows by -2log2e. CONFLICT-FREE: thread writes one full
// 16-B block at linearly increasing LDS address (old word-wise version cost
// 5.85M bank-conflict cycles). Frag mapping preserved: frag f = g*8+ct*2+ch;
// lane (kg*16+l15) holds col=ct*16+l15, k=ch*32+kg*8+j.
__device__ __forceinline__ void stage_main(const float* __restrict__ W, char* smem, int tid)
{
#pragma unroll
    for (int it = 0; it < 6; ++it) {
        int a16   = it*256 + tid;          // 16-B block index in [0,1536)
        int f     = a16 >> 6;              // frag 0..23
        int lanew = a16 & 63;              // dest lane slot
        int colf  = lanew & 15;
        int kb4   = lanew >> 4;
        int ch    = f & 1;
        int ct    = (f >> 1) & 3;
        int g     = f >> 3;
        int gc    = g*64 + ct*16 + colf;   // weight row 0..191
        int k0    = ch*32 + kb4*8;
        float sc  = (g < 2) ? -L1C : -L2C;
        const float* p = W + gc*64 + k0;
        float4 a = *(const float4*)p;
        float4 b = *(const float4*)(p+4);
        h8v v;
        v[0]=(_Float16)(sc*a.x); v[1]=(_Float16)(sc*a.y);
        v[2]=(_Float16)(sc*a.z); v[3]=(_Float16)(sc*a.w);
        v[4]=(_Float16)(sc*b.x); v[5]=(_Float16)(sc*b.y);
        v[6]=(_Float16)(sc*b.z); v[7]=(_Float16)(sc*b.w);
        *(h8v*)(smem + BOFF + a16*16) = v;
    }
}

// One recurrence step for one wave: 36 MFMA + gate algebra, 16 rows x 64 cols.
// bb = smem + lane*16 (main frags), eb = smem + EOFF + (lane&15)*16 (ext frags),
// wp = h-plane write base, hreg = fp32 carry [ct][i].
__device__ __forceinline__ void rnn_step(h8v Aeh, h8v Ah0, h8v Ah1,
                                         const char* bb, const char* eb,
                                         const float cbh[4], float (&hreg)[4][4],
                                         char* wp)
{
    const f4v Z0 = {0.f,0.f,0.f,0.f};
#pragma unroll
    for (int ct = 0; ct < 4; ++ct) {
        f4v a0 = MFMA(Aeh, *(const h8v*)(eb + ct*256),       Z0);   // r: ext (Wih,b)
        a0 = MFMA(Ah0, *(const h8v*)(bb + (ct*2   )*1024), a0);     // r: Whh ch0
        a0 = MFMA(Ah1, *(const h8v*)(bb + (ct*2+1 )*1024), a0);     // r: Whh ch1
        f4v a1 = MFMA(Aeh, *(const h8v*)(eb + (4+ct)*256),   Z0);   // z
        a1 = MFMA(Ah0, *(const h8v*)(bb + (8+ct*2 )*1024), a1);
        a1 = MFMA(Ah1, *(const h8v*)(bb + (9+ct*2 )*1024), a1);
        f4v a3 = MFMA(Aeh, *(const h8v*)(eb + (8+ct)*256),   Z0);   // n: gi part
        f4v a2 = MFMA(Ah0, *(const h8v*)(bb + (16+ct*2)*1024), Z0); // n: Whh.h
        a2 = MFMA(Ah1, *(const h8v*)(bb + (17+ct*2)*1024), a2);
#pragma unroll
        for (int i = 0; i < 4; ++i) {
            float er = exp2_f(a0[i]);
            float rr = rcp_f(1.0f + er);
            float ez = exp2_f(a1[i]);
            float en = exp2_f(fmaf(rr, a2[i] + cbh[ct], a3[i]));
            float h  = hreg[ct][i];
            float aa = 1.0f + ez;
            float den = fmaf(en, aa, aa);        // (1+en)(1+ez)
            float t1  = fmaf(-en, ez, ez);       // ez(1-en)
            float t2  = fmaf(en, h, h);          // h(1+en)
            float hnew = (t1 + t2) * rcp_f(den);
            hreg[ct][i] = hnew;
            *(_Float16*)(wp + i*144 + 32*ct) = (_Float16)hnew;
        }
    }
}

__global__ void __launch_bounds__(256, 4) krnn_kernel(
    const float* __restrict__ X,
    const float* __restrict__ eWih, const float* __restrict__ eWhh,
    const float* __restrict__ ebih, const float* __restrict__ ebhh,
    const float* __restrict__ dWih, const float* __restrict__ dWhh,
    const float* __restrict__ dbih, const float* __restrict__ dbhh,
    const float* __restrict__ linW, const float* __restrict__ linb,
    const float* __restrict__ embed, float* __restrict__ ws)
{
    __shared__ __align__(16) char smem[SMEMSZ];

    const int c    = blockIdx.y;
    const int row0 = blockIdx.x * 64;           // 64 rows per block (4 waves x 16)
    const int tid  = threadIdx.x;
    const int lane = tid & 63;
    const int w    = tid >> 6;
    const int l15  = lane & 15;
    const int kg   = lane >> 4;

    // ---------------- stage encoder weights / x / softmax / h=0 ----------------
    stage_main(eWhh + c*12288, smem, tid);

    if (tid < 192) {                            // enc ext: k0=Wih0,k1=Wih1,k2=bias
        int e = tid >> 4, ln = tid & 15;
        int g = e >> 2, ct = e & 3;
        int gc = g*64 + ct*16 + ln;
        float sc = (g < 2) ? -L1C : -L2C;
        float w0 = eWih[c*384 + gc*2], w1 = eWih[c*384 + gc*2 + 1];
        float bb_ = (g < 2) ? (ebih[c*192+gc] + ebhh[c*192+gc]) : ebih[c*192+gc];
        unsigned short* d = (unsigned short*)(smem + EOFF + e*256 + ln*16);
        d[0] = f16u(sc*w0); d[1] = f16u(sc*w1); d[2] = f16u(sc*bb_);
        d[3]=0; d[4]=0; d[5]=0; d[6]=0; d[7]=0;
    }
    for (int i = tid; i < 768; i += 256) {      // x: packed f16 (x0,x1) per (row,t)
        int r = i / 12, t = i - r*12;
        int rg = row0 + r; if (rg >= BN_) rg = BN_-1;
        const float* p = X + (size_t)rg*24 + t*2;
        unsigned v = (unsigned)f16u(p[0]) | ((unsigned)f16u(p[1]) << 16);
        *(unsigned*)(smem + XOFF + r*48 + t*4) = v;
    }
    if (tid < 64) {                             // softmax weight per row
        int r = row0 + tid; if (r >= BN_) r = BN_-1;
        int n = r % N_;
        float e[10], mx = -1e30f;
#pragma unroll
        for (int cc=0; cc<10; ++cc){ e[cc]=embed[n*10+cc]; mx=fmaxf(mx,e[cc]); }
        float den = 0.0f;
#pragma unroll
        for (int cc=0; cc<10; ++cc) den += exp2_f((e[cc]-mx)*L1C);
        *(float*)(smem + WOFF + tid*4) = exp2_f((e[c]-mx)*L1C) * rcp_f(den);
    }
    for (int i = tid; i < 2304; i += 256)       // zero all h planes (incl. pad)
        *(unsigned*)(smem + HOFF + i*4) = 0u;

    float cbh[4];                               // n-gate bhh per owned col (fp32)
#pragma unroll
    for (int ct=0; ct<4; ++ct) cbh[ct] = -L2C * ebhh[c*192 + 128 + l15 + 16*ct];

    __syncthreads();                            // barrier 1/3

    float wreg[4];
#pragma unroll
    for (int i=0;i<4;++i) wreg[i] = *(const float*)(smem + WOFF + (w*16 + kg*4 + i)*4);

    char* hp = smem + HOFF + w*2304;            // private h plane
    const int rdo = l15*144 + kg*16;            // A-frag read offset (+64 for ch1)
    char* wp = hp + kg*576 + l15*2;             // gate write base
    const char* bb = smem + lane*16;            // main frag base
    const char* eb = smem + EOFF + l15*16;      // ext frag base (broadcast reads)

    float hreg[4][4];
#pragma unroll
    for (int ct=0; ct<4; ++ct)
#pragma unroll
        for (int i=0;i<4;++i) hreg[ct][i] = 0.0f;

    // ---------------- encoder: 12 barrier-free steps ----------------
    for (int t = 0; t < 12; ++t) {
        unsigned xd = *(const unsigned*)(smem + XOFF + (w*16 + l15)*48 + t*4);
        union { u32x4 u; h8v h; } ae;
        ae.u.x = (lane < 16) ? xd : 0u;         // k0=x0, k1=x1
        ae.u.y = (lane < 16) ? 0x00003C00u : 0u;// k2=1.0
        ae.u.z = 0u; ae.u.w = 0u;
        h8v Ah0 = *(const h8v*)(hp + rdo);
        h8v Ah1 = *(const h8v*)(hp + rdo + 64);
        rnn_step(ae.h, Ah0, Ah1, bb, eb, cbh, hreg, wp);
    }

    // lv0 = f16(x[t=11].x) packed with 1.0 for the dec A-ext, before restage
    unsigned aew = (*(const unsigned*)(smem + XOFF + (w*16 + l15)*48 + 44) & 0xFFFFu)
                   | 0x3C000000u;

    __syncthreads();                            // barrier 2/3 (all enc reads done)

    // ---------------- stage decoder weights ----------------
    stage_main(dWhh + c*12288, smem, tid);
    if (tid < 192) {                            // dec ext: k0=Wih, k1=bias
        int e = tid >> 4, ln = tid & 15;
        int g = e >> 2, ct = e & 3;
        int gc = g*64 + ct*16 + ln;
        float k0, k1;
        if (g < 2) { k0 = -L1C*dWih[c*192+gc]; k1 = -L1C*(dbih[c*192+gc]+dbhh[c*192+gc]); }
        else       { k0 = -L2C*dWih[c*192+gc]; k1 = -L2C*dbih[c*192+gc]; }
        unsigned short* d = (unsigned short*)(smem + EOFF + e*256 + ln*16);
        d[0] = f16u(k0); d[1] = f16u(k1);
        d[2]=0; d[3]=0; d[4]=0; d[5]=0; d[6]=0; d[7]=0;
    }
    if (tid < 128) {                            // linW B-frags (cols replicated)
        int ch = tid >> 6, ln = tid & 63;
        int kb = ch*32 + (ln >> 4)*8;
        unsigned short* d = (unsigned short*)(smem + LWOFF + ch*1024 + ln*16);
#pragma unroll
        for (int j=0;j<8;++j) d[j] = f16u(linW[c*64 + kb + j]);
    }
#pragma unroll
    for (int ct=0; ct<4; ++ct) cbh[ct] = -L2C * dbhh[c*192 + 128 + l15 + 16*ct];
    const float lb = linb[c];
    float* __restrict__ wsc = ws + (size_t)c * OUTSZ_;

    __syncthreads();                            // barrier 3/3

    // ---------------- decoder: 12 barrier-free steps ----------------
    for (int s = 0; s < 12; ++s) {
        h8v Ah0 = *(const h8v*)(hp + rdo);
        h8v Ah1 = *(const h8v*)(hp + rdo + 64);
        if (s > 0) {
            const f4v Zv = {0.f,0.f,0.f,0.f};
            f4v av = MFMA(Ah0, *(const h8v*)(smem + LWOFF + lane*16), Zv);
            av = MFMA(Ah1, *(const h8v*)(smem + LWOFF + 1024 + lane*16), av);
            if (l15 == 0) {                     // lanes 0,16,32,48 own rows kg*4+i
#pragma unroll
                for (int i=0;i<4;++i) {
                    float lv = av[i] + lb;      // v_{s-1}
                    *(float*)(smem + LOFF + w*64 + (kg*4+i)*4) = lv;
                    int r = row0 + w*16 + kg*4 + i;
                    if (r < BN_) wsc[(size_t)r*12 + (s-1)] = wreg[i]*lv;
                }
            }
            float lvme = *(const float*)(smem + LOFF + w*64 + l15*4); // intra-wave
            aew = (unsigned)f16u(lvme) | 0x3C000000u;   // k0=lv, k1=1.0
        }
        union { u32x4 u; h8v h; } ae;
        ae.u.x = (lane < 16) ? aew : 0u;
        ae.u.y = 0u; ae.u.z = 0u; ae.u.w = 0u;
        rnn_step(ae.h, Ah0, Ah1, bb, eb, cbh, hreg, wp);
    }

    // ---------------- epilogue: v_11 from h_11 ----------------
    {
        h8v Ah0 = *(const h8v*)(hp + rdo);
        h8v Ah1 = *(const h8v*)(hp + rdo + 64);
        const f4v Zv = {0.f,0.f,0.f,0.f};
        f4v av = MFMA(Ah0, *(const h8v*)(smem + LWOFF + lane*16), Zv);
        av = MFMA(Ah1, *(const h8v*)(smem + LWOFF + 1024 + lane*16), av);
        if (l15 == 0) {
#pragma unroll
            for (int i=0;i<4;++i) {
                float lv = av[i] + lb;
                int r = row0 + w*16 + kg*4 + i;
                if (r < BN_) wsc[(size_t)r*12 + 11] = wreg[i]*lv;
            }
        }
    }
}

// Mix over clusters: out[i] = sum_c ws[c][i]. ws is 5 MB, L2/L3-hot.
__global__ void __launch_bounds__(256) mix_kernel(const float* __restrict__ ws,
                                                  float* __restrict__ out)
{
    int i = blockIdx.x * 256 + threadIdx.x;
    if (i < OUTSZ_) {
        float s = 0.0f;
#pragma unroll
        for (int c = 0; c < 10; ++c) s += ws[(size_t)c * OUTSZ_ + i];
        out[i] = s;
    }
}

extern "C" void kernel_launch(void* const* d_in, const int* in_sizes, int n_in,
                              void* d_out, int out_size, void* d_ws, size_t ws_size,
                              hipStream_t stream) {
    // 0:A 1:X 2:enc_Wih 3:enc_Whh 4:enc_bih 5:enc_bhh
    // 6:dec_Wih 7:dec_Whh 8:dec_bih 9:dec_bhh 10:lin_W 11:lin_b 12:embed
    const float* X    = (const float*)d_in[1];
    const float* eWih = (const float*)d_in[2];
    const float* eWhh = (const float*)d_in[3];
    const float* ebih = (const float*)d_in[4];
    const float* ebhh = (const float*)d_in[5];
    const float* dWih = (const float*)d_in[6];
    const float* dWhh = (const float*)d_in[7];
    const float* dbih = (const float*)d_in[8];
    const float* dbhh = (const float*)d_in[9];
    const float* linW = (const float*)d_in[10];
    const float* linb = (const float*)d_in[11];
    const float* emb  = (const float*)d_in[12];
    float* ws  = (float*)d_ws;
    float* out = (float*)d_out;

    dim3 grid((BN_ + 63) / 64, 10);   // 163 x 10 blocks, 4 independent waves each
    krnn_kernel<<<grid, dim3(256), 0, stream>>>(
        X, eWih, eWhh, ebih, ebhh, dWih, dWhh, dbih, dbhh, linW, linb, emb, ws);
    mix_kernel<<<(OUTSZ_ + 255) / 256, dim3(256), 0, stream>>>(ws, out);
}